// Round 9
// baseline (832.108 us; speedup 1.0000x reference)
//
#include <hip/hip_runtime.h>
#include <stdint.h>

#define B_    4
#define N_    2048
#define D_    4096
#define E_    64
#define TOKENS (B_ * N_)        // 8192
#define KT    16                // K-tile per LDS buffer
#define TM    64                // tokens per block tile
#define KS    8                 // split-K factor
#define KCHUNK (D_ / KS)        // 512
#define NIT   (KCHUNK / KT)     // 32 K-tiles per block
#define PA    (TM + 4)          // As pitch 68: 16B-aligned, conflict-free reads

// ---------------------------------------------------------------------------
// K1: split-K fp32 GEMM, double-buffered LDS, ONE barrier per K-tile.
// 256 thr, tile 64 tok x 64 exp, thread tile 4x4.
// Iteration: commit prefetched regs -> barrier -> issue next tile's global
// loads -> compute. Parity: a buffer is only overwritten two barriers after
// it was last read, so one barrier/iter is race-free. Prefetched loads stay
// in flight across the whole compute phase (vmcnt-tracked).
// __launch_bounds__(256,6): 6 blocks/CU = 24 waves/CU for latency hiding.
// ---------------------------------------------------------------------------
__global__ __launch_bounds__(256, 6) void k_gemm(const float* __restrict__ A,
                                                 const float* __restrict__ W,
                                                 float* __restrict__ P) {
    __shared__ float As[2][KT][PA];   // transposed: As[buf][k][tok]
    __shared__ float Ws[2][KT][E_];   // natural:    Ws[buf][k][e]

    const int tid   = threadIdx.x;
    const int tok0  = blockIdx.x * TM;
    const int kc    = blockIdx.y;
    const int kbase = kc * KCHUNK;

    // compute mapping: 4 tok x 4 exp per thread
    const int t0 = (tid & 15) * 4;
    const int e0 = (tid >> 4) * 4;

    // staging mapping
    const int a_t  = tid >> 2;           // token 0..63
    const int a_kf = (tid & 3) * 4;      // k offset 0..12
    const int w_kk = tid >> 4;           // k row 0..15
    const int w_e  = (tid & 15) * 4;     // expert 0..60

    const float* gA = A + (size_t)(tok0 + a_t) * D_ + kbase + a_kf;
    const float* gW = W + (size_t)(kbase + w_kk) * E_ + w_e;

    // prologue: tile 0 into registers
    float4 ra = *reinterpret_cast<const float4*>(gA);
    float4 rw = *reinterpret_cast<const float4*>(gW);

    float acc[4][4] = {{0.f}};

    #pragma unroll 2
    for (int it = 0; it < NIT; ++it) {
        const int cur = it & 1;

        // commit prefetched tile to LDS buffer `cur`
        As[cur][a_kf + 0][a_t] = ra.x;
        As[cur][a_kf + 1][a_t] = ra.y;
        As[cur][a_kf + 2][a_t] = ra.z;
        As[cur][a_kf + 3][a_t] = ra.w;
        *reinterpret_cast<float4*>(&Ws[cur][w_kk][w_e]) = rw;
        __syncthreads();                       // the ONLY barrier per iter

        // issue next tile's global loads — in flight during compute
        if (it + 1 < NIT) {
            ra = *reinterpret_cast<const float4*>(gA + (it + 1) * KT);
            rw = *reinterpret_cast<const float4*>(gW + (size_t)(it + 1) * KT * E_);
        }

        #pragma unroll
        for (int kk = 0; kk < KT; ++kk) {
            const float4 a = *reinterpret_cast<const float4*>(&As[cur][kk][t0]);
            const float4 b = *reinterpret_cast<const float4*>(&Ws[cur][kk][e0]);
            acc[0][0] += a.x * b.x; acc[0][1] += a.x * b.y;
            acc[0][2] += a.x * b.z; acc[0][3] += a.x * b.w;
            acc[1][0] += a.y * b.x; acc[1][1] += a.y * b.y;
            acc[1][2] += a.y * b.z; acc[1][3] += a.y * b.w;
            acc[2][0] += a.z * b.x; acc[2][1] += a.z * b.y;
            acc[2][2] += a.z * b.z; acc[2][3] += a.z * b.w;
            acc[3][0] += a.w * b.x; acc[3][1] += a.w * b.y;
            acc[3][2] += a.w * b.z; acc[3][3] += a.w * b.w;
        }
        // no second barrier: next iter's commit targets the other buffer
    }

    float* base = P + ((size_t)kc * TOKENS + tok0) * E_;
    #pragma unroll
    for (int i = 0; i < 4; ++i) {
        const float4 v = make_float4(acc[i][0], acc[i][1], acc[i][2], acc[i][3]);
        *reinterpret_cast<float4*>(&base[(size_t)(t0 + i) * E_ + e0]) = v;
    }
}

// ---------------------------------------------------------------------------
// K2: reduce split-K partials; per-token softmax stats (wave per token, lane =
// expert). Writes argmax idx, gate (=max prob), accumulates probsum[b][e] and
// the z-loss (atomic, pre-scaled).
// ---------------------------------------------------------------------------
__global__ __launch_bounds__(256) void k_softmax(const float* __restrict__ P,
                                                 int* __restrict__ idx,
                                                 float* __restrict__ gate,
                                                 float* __restrict__ probsum,
                                                 float* __restrict__ out_z) {
    const int tid  = threadIdx.x;
    const int wid  = tid >> 6;
    const int lane = tid & 63;
    const int tok  = blockIdx.x * 4 + wid;

    float l = 0.f;
    #pragma unroll
    for (int kc = 0; kc < KS; ++kc)
        l += P[((size_t)kc * TOKENS + tok) * E_ + lane];

    // wave argmax, first-index tie-break (matches numpy)
    float m = l; int mi = lane;
    #pragma unroll
    for (int off = 32; off > 0; off >>= 1) {
        const float om = __shfl_down(m, off);
        const int   oi = __shfl_down(mi, off);
        if (om > m || (om == m && oi < mi)) { m = om; mi = oi; }
    }
    m  = __shfl(m, 0);
    mi = __shfl(mi, 0);

    const float p = __expf(l - m);
    float s = p;
    #pragma unroll
    for (int off = 32; off > 0; off >>= 1) s += __shfl_down(s, off);
    s = __shfl(s, 0);

    __shared__ float pacc[4][E_];
    __shared__ float zv[4];
    pacc[wid][lane] = p / s;
    if (lane == 0) {
        const float lse = m + logf(s);
        zv[wid]   = lse * lse;
        idx[tok]  = mi;
        gate[tok] = 1.0f / s;                 // exp(m-m)/s = max prob
    }
    __syncthreads();

    if (tid < E_) {
        const float ps = pacc[0][tid] + pacc[1][tid] + pacc[2][tid] + pacc[3][tid];
        const int b = (blockIdx.x * 4) / N_;  // block never crosses batch
        atomicAdd(&probsum[b * E_ + tid], ps);
    }
    if (tid == 0)
        atomicAdd(out_z, (zv[0] + zv[1] + zv[2] + zv[3]) * (1.0f / (float)TOKENS));
}

// ---------------------------------------------------------------------------
// K3: ordered position-in-expert via wave ballot (matches reference cumsum),
// scatter into dispatch/combine + aux-loss fused. One wave per (b,e).
// ---------------------------------------------------------------------------
__global__ __launch_bounds__(64) void k_posloss(const int* __restrict__ idx,
                                                const float* __restrict__ gate,
                                                const float* __restrict__ probsum,
                                                float* __restrict__ out,
                                                float* __restrict__ out_aux,
                                                int C, size_t half) {
    const int b = blockIdx.x >> 6;
    const int e = blockIdx.x & 63;
    const int lane = threadIdx.x;
    const int*   ib = idx  + b * N_;
    const float* gb = gate + b * N_;
    float* ob = out + (size_t)b * N_ * E_ * C;   // dispatch base for batch b

    int running = 0;
    for (int step = 0; step < N_ / 64; ++step) {
        const int t = step * 64 + lane;
        const bool match = (ib[t] == e);
        const unsigned long long mask = __ballot(match);
        if (match) {
            const int p = running + __popcll(mask & ((1ull << lane) - 1ull));
            if (p < C) {
                const size_t off = (size_t)t * E_ * C + (size_t)e * C + p;
                ob[off] = 1.0f;            // dispatch
                ob[half + off] = gb[t];    // combine
            }
        }
        running += __popcll(mask);
    }
    if (lane == 0)   // aux = sum(count * probsum) * E^2/(B*E*N*N) = sum/262144
        atomicAdd(out_aux,
                  (float)running * probsum[b * E_ + e] * (1.0f / 262144.0f));
}

// ---------------------------------------------------------------------------
extern "C" void kernel_launch(void* const* d_in, const int* in_sizes, int n_in,
                              void* d_out, int out_size, void* d_ws, size_t ws_size,
                              hipStream_t stream) {
    const float* A = (const float*)d_in[0];
    const float* W = (const float*)d_in[1];
    float* out = (float*)d_out;

    const size_t half = ((size_t)out_size - 2) / 2;          // TOKENS*E*C
    const int C = (int)(half / ((size_t)TOKENS * E_));       // 40

    float* P = (float*)d_ws;
    size_t off = (size_t)KS * TOKENS * E_;
    int*   idx     = (int*)(P + off);   off += TOKENS;
    float* gate    = P + off;           off += TOKENS;
    float* probsum = P + off;           off += B_ * E_;

    float* out_aux = out + 2 * half;
    float* out_z   = out + 2 * half + 1;

    hipMemsetAsync(d_out, 0, (size_t)out_size * sizeof(float), stream);
    hipMemsetAsync(probsum, 0, B_ * E_ * sizeof(float), stream);

    k_gemm<<<dim3(TOKENS / TM, KS), 256, 0, stream>>>(A, W, P);
    k_softmax<<<TOKENS / 4, 256, 0, stream>>>(P, idx, gate, probsum, out_z);
    k_posloss<<<B_ * E_, 64, 0, stream>>>(idx, gate, probsum, out, out_aux, C, half);
}